// Round 1
// baseline (162.537 us; speedup 1.0000x reference)
//
#include <hip/hip_runtime.h>

// PAB3D on MI355X (gfx950).
// Shapes: B=2, C=P=64, H=W=D=16, N=4096.
// Pipeline:
//  k_prep_w : cast/transpose weights to bf16 MFMA A-layout [k27][co][ci]
//  k_xt<0>  : x [b][c][n] f32 -> xT [b][n][c] bf16 (LDS transpose)
//  k_conv<1,0>  : top/center 1x1x1 conv -> T-layout bf16 [b][n][p]
//  k_conv<27,2> : bottom 3x3x3 conv -> std layout bf16 [b][c][n]
//  k_pass1  : S=cen^T@top tiles (MFMA), per-64x64-tile (max, sum exp)
//  k_reduce : global (M, 1/Z) per batch
//  k_pass2  : recompute S tiles, P=exp(S-M), LDS-transpose, P@bottom^T -> sp
//  k_xt<1>  : yT = bf16(x + sp_reshaped)
//  k_conv<27,1> : out conv -> d_out f32

typedef __attribute__((ext_vector_type(8))) short bf16x8;
typedef __attribute__((ext_vector_type(4))) short short4v;
typedef __attribute__((ext_vector_type(4))) float f32x4;

#define DEVI static __device__ __forceinline__
#define MFMA16(a, b, c) __builtin_amdgcn_mfma_f32_16x16x32_bf16((a), (b), (c), 0, 0, 0)

DEVI unsigned short f2bf(float f) {  // RNE float->bf16
  unsigned u = __float_as_uint(f);
  return (unsigned short)((u + 0x7fffu + ((u >> 16) & 1u)) >> 16);
}

// ---------------- weight prep ----------------
__global__ void k_prep_w(const float* __restrict__ tw, const float* __restrict__ cw,
                         const float* __restrict__ bw, const float* __restrict__ ow,
                         unsigned short* __restrict__ wkTop, unsigned short* __restrict__ wkCen,
                         unsigned short* __restrict__ wkBot, unsigned short* __restrict__ wkOut) {
  int t = blockIdx.x * 256 + threadIdx.x;
  if (t < 4096) {  // [p][c] layouts already A-friendly (ci contiguous)
    wkTop[t] = f2bf(tw[t]);
    wkCen[t] = f2bf(cw[t]);
  }
  if (t < 110592) {  // src [co][ci][k27] -> dst [k27][co][ci]
    int k = t % 27;
    int ci = (t / 27) & 63;
    int co = t / (27 * 64);
    int dst = (k * 64 + co) * 64 + ci;
    wkBot[dst] = f2bf(bw[t]);
    wkOut[dst] = f2bf(ow[t]);
  }
}

// ---------------- transpose/cast x (optionally + sp "buggy reshape") ----------------
template <int ADD_SP>
__global__ void k_xt(const float* __restrict__ x, const float* __restrict__ sp,
                     unsigned short* __restrict__ xT) {
  __shared__ float tile[64][65];
  int bx = blockIdx.x;
  int b = bx >> 6;
  int n0 = (bx & 63) << 6;
  int t = threadIdx.x;
  {
    int nl = t & 63, cq = t >> 6;
    const float* xb = x + (size_t)b * 262144;
#pragma unroll
    for (int j = 0; j < 16; j++) {
      int c = cq * 16 + j;
      float v = xb[(size_t)c * 4096 + n0 + nl];
      if (ADD_SP) v += sp[(size_t)b * 262144 + (size_t)c * 4096 + n0 + nl];
      tile[c][nl] = v;
    }
  }
  __syncthreads();
  {
    int n = t >> 2, c0 = (t & 3) << 4;
    bf16x8 o0, o1;
#pragma unroll
    for (int j = 0; j < 8; j++) {
      o0[j] = (short)f2bf(tile[c0 + j][n]);
      o1[j] = (short)f2bf(tile[c0 + 8 + j][n]);
    }
    unsigned short* dst = xT + ((size_t)(b * 4096 + n0 + n)) * 64 + c0;
    *(bf16x8*)(dst) = o0;
    *(bf16x8*)(dst + 8) = o1;
  }
}

// ---------------- conv as 27 shifted pointwise GEMMs (MFMA) ----------------
// OMODE 0: bf16 T-layout [b][n][co]; OMODE 2: bf16 [b][co][n]; OMODE 1: f32 [b][co][n]
template <int NK, int OMODE>
__global__ void k_conv(const unsigned short* __restrict__ wk,
                       const unsigned short* __restrict__ xTb,
                       const float* __restrict__ bias,
                       float* __restrict__ outF, unsigned short* __restrict__ outH) {
  int bx = blockIdx.x;
  int b = bx >> 7;
  int n0 = (bx & 127) << 5;  // 32 voxels per block
  int t = threadIdx.x;
  int lane = t & 63, wid = t >> 6;
  int col = lane & 15, kg = lane >> 4;
  int co0 = wid << 4;
  const unsigned short* xb = xTb + (size_t)b * 262144;

  int n0c = n0 + col, n1c = n0 + 16 + col;
  int h0 = n0c >> 8, w0 = (n0c >> 4) & 15, dd0 = n0c & 15;
  int h1 = n1c >> 8, w1 = (n1c >> 4) & 15, dd1 = n1c & 15;

  f32x4 acc0 = {0.f, 0.f, 0.f, 0.f}, acc1 = {0.f, 0.f, 0.f, 0.f};
#pragma unroll
  for (int k = 0; k < NK; k++) {
    const int dh = (NK == 1) ? 0 : (k / 9 - 1);
    const int dw = (NK == 1) ? 0 : ((k / 3) % 3 - 1);
    const int dz = (NK == 1) ? 0 : (k % 3 - 1);
    bool v0 = ((unsigned)(h0 + dh) < 16u) & ((unsigned)(w0 + dw) < 16u) & ((unsigned)(dd0 + dz) < 16u);
    bool v1 = ((unsigned)(h1 + dh) < 16u) & ((unsigned)(w1 + dw) < 16u) & ((unsigned)(dd1 + dz) < 16u);
    int np0 = n0c + dh * 256 + dw * 16 + dz;
    int np1 = n1c + dh * 256 + dw * 16 + dz;
#pragma unroll
    for (int kc = 0; kc < 2; kc++) {
      bf16x8 av = *(const bf16x8*)(wk + ((size_t)(k * 64 + co0 + col) * 64 + kc * 32 + kg * 8));
      bf16x8 b0 = {0, 0, 0, 0, 0, 0, 0, 0};
      if (v0) b0 = *(const bf16x8*)(xb + (size_t)np0 * 64 + kc * 32 + kg * 8);
      acc0 = MFMA16(av, b0, acc0);
      bf16x8 b1 = {0, 0, 0, 0, 0, 0, 0, 0};
      if (v1) b1 = *(const bf16x8*)(xb + (size_t)np1 * 64 + kc * 32 + kg * 8);
      acc1 = MFMA16(av, b1, acc1);
    }
  }
  float bv[4];
#pragma unroll
  for (int r = 0; r < 4; r++) bv[r] = bias[co0 + kg * 4 + r];

  if (OMODE == 0) {
    short4v s0, s1;
#pragma unroll
    for (int r = 0; r < 4; r++) {
      s0[r] = (short)f2bf(acc0[r] + bv[r]);
      s1[r] = (short)f2bf(acc1[r] + bv[r]);
    }
    *(short4v*)(outH + (size_t)(b * 4096 + n0c) * 64 + co0 + kg * 4) = s0;
    *(short4v*)(outH + (size_t)(b * 4096 + n1c) * 64 + co0 + kg * 4) = s1;
  } else if (OMODE == 2) {
#pragma unroll
    for (int r = 0; r < 4; r++) {
      int co = co0 + kg * 4 + r;
      outH[(size_t)(b * 64 + co) * 4096 + n0c] = f2bf(acc0[r] + bv[r]);
      outH[(size_t)(b * 64 + co) * 4096 + n1c] = f2bf(acc1[r] + bv[r]);
    }
  } else {
#pragma unroll
    for (int r = 0; r < 4; r++) {
      int co = co0 + kg * 4 + r;
      outF[(size_t)(b * 64 + co) * 4096 + n0c] = acc0[r] + bv[r];
      outF[(size_t)(b * 64 + co) * 4096 + n1c] = acc1[r] + bv[r];
    }
  }
}

// ---------------- pass 1: per-tile softmax stats over S = cen^T @ top ----------------
__global__ void k_pass1(const unsigned short* __restrict__ cenT,
                        const unsigned short* __restrict__ topT,
                        float* __restrict__ stats) {
  int bx = blockIdx.x;
  int b = bx >> 12;
  int nt = (bx >> 6) & 63;
  int mt = bx & 63;
  int t = threadIdx.x;
  int lane = t & 63, wid = t >> 6;
  int col = lane & 15, kg = lane >> 4;
  const unsigned short* cb = cenT + (size_t)b * 262144;
  const unsigned short* tb = topT + (size_t)b * 262144;
  int n0 = nt * 64 + wid * 16;
  int m0 = mt * 64;
  bf16x8 a0 = *(const bf16x8*)(cb + (size_t)(n0 + col) * 64 + kg * 8);
  bf16x8 a1 = *(const bf16x8*)(cb + (size_t)(n0 + col) * 64 + 32 + kg * 8);
  f32x4 acc[4];
#pragma unroll
  for (int m = 0; m < 4; m++) acc[m] = (f32x4){0.f, 0.f, 0.f, 0.f};
#pragma unroll
  for (int m = 0; m < 4; m++) {
    bf16x8 b0 = *(const bf16x8*)(tb + (size_t)(m0 + m * 16 + col) * 64 + kg * 8);
    bf16x8 b1 = *(const bf16x8*)(tb + (size_t)(m0 + m * 16 + col) * 64 + 32 + kg * 8);
    acc[m] = MFMA16(a0, b0, acc[m]);
    acc[m] = MFMA16(a1, b1, acc[m]);
  }
  float mx = -1e30f;
#pragma unroll
  for (int m = 0; m < 4; m++)
#pragma unroll
    for (int r = 0; r < 4; r++) mx = fmaxf(mx, acc[m][r]);
#pragma unroll
  for (int off = 32; off; off >>= 1) mx = fmaxf(mx, __shfl_xor(mx, off));
  __shared__ float wred[4];
  if (lane == 0) wred[wid] = mx;
  __syncthreads();
  float bm = fmaxf(fmaxf(wred[0], wred[1]), fmaxf(wred[2], wred[3]));
  float s = 0.f;
#pragma unroll
  for (int m = 0; m < 4; m++)
#pragma unroll
    for (int r = 0; r < 4; r++) s += __expf(acc[m][r] - bm);
#pragma unroll
  for (int off = 32; off; off >>= 1) s += __shfl_xor(s, off);
  __syncthreads();
  if (lane == 0) wred[wid] = s;
  __syncthreads();
  if (t == 0) {
    float* o = stats + (size_t)(b * 4096 + nt * 64 + mt) * 2;
    o[0] = bm;
    o[1] = wred[0] + wred[1] + wred[2] + wred[3];
  }
}

// ---------------- global (M, 1/Z) per batch ----------------
__global__ void k_reduce(const float* __restrict__ stats, float* __restrict__ MZ) {
  int b = blockIdx.x;
  int t = threadIdx.x;
  const float* st = stats + (size_t)b * 8192;
  float mx = -1e30f;
  for (int i = t; i < 4096; i += 256) mx = fmaxf(mx, st[2 * i]);
#pragma unroll
  for (int off = 32; off; off >>= 1) mx = fmaxf(mx, __shfl_xor(mx, off));
  __shared__ float red[4];
  if ((t & 63) == 0) red[t >> 6] = mx;
  __syncthreads();
  float M = fmaxf(fmaxf(red[0], red[1]), fmaxf(red[2], red[3]));
  float z = 0.f;
  for (int i = t; i < 4096; i += 256) z += st[2 * i + 1] * __expf(st[2 * i] - M);
#pragma unroll
  for (int off = 32; off; off >>= 1) z += __shfl_xor(z, off);
  __syncthreads();
  if ((t & 63) == 0) red[t >> 6] = z;
  __syncthreads();
  if (t == 0) {
    float Z = red[0] + red[1] + red[2] + red[3];
    MZ[b * 2] = M;
    MZ[b * 2 + 1] = 1.0f / Z;
  }
}

// ---------------- pass 2: O[n][c] = (1/Z) sum_m exp(S-M) * bottom[c][m] ----------------
__global__ void k_pass2(const unsigned short* __restrict__ cenT,
                        const unsigned short* __restrict__ topT,
                        const unsigned short* __restrict__ botS,
                        const float* __restrict__ MZ,
                        float* __restrict__ spf) {
  __shared__ __align__(16) unsigned short plds[4][1024];  // per-wave 16x64 P tile, XOR-swizzled
  __shared__ __align__(16) float osum[4][16][64];
  int bx = blockIdx.x;
  int b = bx >> 8;
  int n0 = (bx & 255) << 4;  // 16 rows per block; waves split m
  int t = threadIdx.x;
  int lane = t & 63, wid = t >> 6;
  int col = lane & 15, kg = lane >> 4;
  const unsigned short* cb = cenT + (size_t)b * 262144;
  const unsigned short* tb = topT + (size_t)b * 262144;
  const unsigned short* bb = botS + (size_t)b * 262144;
  float M = MZ[b * 2], invZ = MZ[b * 2 + 1];

  bf16x8 aS0 = *(const bf16x8*)(cb + (size_t)(n0 + col) * 64 + kg * 8);
  bf16x8 aS1 = *(const bf16x8*)(cb + (size_t)(n0 + col) * 64 + 32 + kg * 8);

  f32x4 accO[4];
#pragma unroll
  for (int ct = 0; ct < 4; ct++) accO[ct] = (f32x4){0.f, 0.f, 0.f, 0.f};

  for (int i = 0; i < 16; i++) {
    int m0 = (i * 4 + wid) << 6;
    f32x4 accS[4];
#pragma unroll
    for (int mt = 0; mt < 4; mt++) accS[mt] = (f32x4){0.f, 0.f, 0.f, 0.f};
#pragma unroll
    for (int mt = 0; mt < 4; mt++) {
      bf16x8 b0 = *(const bf16x8*)(tb + (size_t)(m0 + mt * 16 + col) * 64 + kg * 8);
      bf16x8 b1 = *(const bf16x8*)(tb + (size_t)(m0 + mt * 16 + col) * 64 + 32 + kg * 8);
      accS[mt] = MFMA16(aS0, b0, accS[mt]);
      accS[mt] = MFMA16(aS1, b1, accS[mt]);
    }
    // D-layout -> LDS (swizzled): row = kg*4+reg (n), col = mt*16+col (m)
#pragma unroll
    for (int mt = 0; mt < 4; mt++) {
#pragma unroll
      for (int r = 0; r < 4; r++) {
        int nrow = kg * 4 + r;
        int m = mt * 16 + col;
        float p = __expf(accS[mt][r] - M);
        plds[wid][nrow * 64 + (m ^ ((nrow & 7) << 3))] = f2bf(p);
      }
    }
    // read back as A-frags (16B contiguous thanks to 16B-granular XOR), MFMA with bottom
#pragma unroll
    for (int kc = 0; kc < 2; kc++) {
      bf16x8 pa = *(const bf16x8*)&plds[wid][col * 64 + ((kc * 32 + kg * 8) ^ ((col & 7) << 3))];
#pragma unroll
      for (int ct = 0; ct < 4; ct++) {
        bf16x8 bv = *(const bf16x8*)(bb + (size_t)(ct * 16 + col) * 4096 + m0 + kc * 32 + kg * 8);
        accO[ct] = MFMA16(pa, bv, accO[ct]);
      }
    }
  }
#pragma unroll
  for (int ct = 0; ct < 4; ct++)
#pragma unroll
    for (int r = 0; r < 4; r++) osum[wid][kg * 4 + r][ct * 16 + col] = accO[ct][r];
  __syncthreads();
  const f32x4* o0 = (const f32x4*)&osum[0][0][0];
  const f32x4* o1 = (const f32x4*)&osum[1][0][0];
  const f32x4* o2 = (const f32x4*)&osum[2][0][0];
  const f32x4* o3 = (const f32x4*)&osum[3][0][0];
  f32x4 r4 = o0[t] + o1[t] + o2[t] + o3[t];
  f32x4 rr;
#pragma unroll
  for (int j = 0; j < 4; j++) rr[j] = r4[j] * invZ;
  ((f32x4*)(spf + (size_t)b * 262144 + (size_t)n0 * 64))[t] = rr;
}

// ---------------- host ----------------
extern "C" void kernel_launch(void* const* d_in, const int* in_sizes, int n_in,
                              void* d_out, int out_size, void* d_ws, size_t ws_size,
                              hipStream_t stream) {
  const float* x = (const float*)d_in[0];
  const float* tw = (const float*)d_in[1];
  const float* tb = (const float*)d_in[2];
  const float* cw = (const float*)d_in[3];
  const float* cbb = (const float*)d_in[4];
  const float* bw = (const float*)d_in[5];
  const float* bb = (const float*)d_in[6];
  const float* ow = (const float*)d_in[7];
  const float* ob = (const float*)d_in[8];
  float* out = (float*)d_out;
  char* ws = (char*)d_ws;

  unsigned short* wkTop = (unsigned short*)(ws + 0);        // 8 KB
  unsigned short* wkCen = (unsigned short*)(ws + 8192);     // 8 KB
  unsigned short* wkBot = (unsigned short*)(ws + 16384);    // 216 KB
  unsigned short* wkOut = (unsigned short*)(ws + 237568);   // 216 KB
  unsigned short* xT = (unsigned short*)(ws + 458752);      // 1 MB
  unsigned short* topT = (unsigned short*)(ws + 1507328);   // 1 MB
  unsigned short* cenT = (unsigned short*)(ws + 2555904);   // 1 MB
  unsigned short* botS = (unsigned short*)(ws + 3604480);   // 1 MB
  unsigned short* yT = (unsigned short*)(ws + 4653056);     // 1 MB
  float* spf = (float*)(ws + 5701632);                      // 2 MB
  float* stats = (float*)(ws + 7798784);                    // 64 KB
  float* MZ = (float*)(ws + 7864320);                       // 16 B

  k_prep_w<<<432, 256, 0, stream>>>(tw, cw, bw, ow, wkTop, wkCen, wkBot, wkOut);
  k_xt<0><<<128, 256, 0, stream>>>(x, spf, xT);
  k_conv<1, 0><<<256, 256, 0, stream>>>(wkTop, xT, tb, nullptr, topT);
  k_conv<1, 0><<<256, 256, 0, stream>>>(wkCen, xT, cbb, nullptr, cenT);
  k_conv<27, 2><<<256, 256, 0, stream>>>(wkBot, xT, bb, nullptr, botS);
  k_pass1<<<8192, 256, 0, stream>>>(cenT, topT, stats);
  k_reduce<<<2, 256, 0, stream>>>(stats, MZ);
  k_pass2<<<512, 256, 0, stream>>>(cenT, topT, botS, MZ, spf);
  k_xt<1><<<128, 256, 0, stream>>>(x, spf, yT);
  k_conv<27, 1><<<256, 256, 0, stream>>>(wkOut, yT, ob, out, nullptr);
}